// Round 8
// baseline (171.521 us; speedup 1.0000x reference)
//
#include <hip/hip_runtime.h>
#include <hip/hip_cooperative_groups.h>

// Problem constants (match reference)
#define BQ 32
#define TT 20000
#define NN 200
#define S3 600               // 3*N
#define NXCD 8
#define BPX 128              // blocks per xcd-label
#define COOP_GRID (NXCD * BPX)   // 1024 blocks = 4/CU (co-resident w/ launch_bounds(256,4))
#define JR 40                // j's per repack tile
#define NJT (NN / JR)        // 5
#define TILES (NN * NJT)     // 1000 tiles per xcd-label
#define RX_HALFS ((size_t)NN * NN * 36)        // 1,440,000 halfs per xcd slice (2.88 MB)
#define R_HALFS  (RX_HALFS * NXCD)             // 11,520,000 halfs total (23.04 MB)

typedef float    f32x4 __attribute__((ext_vector_type(4)));
typedef _Float16 f16x8 __attribute__((ext_vector_type(8)));
typedef _Float16 f16x2 __attribute__((ext_vector_type(2)));

// ---------------------------------------------------------------------------
// Shared compute: four distinct products T2[u][v] = Mij * S^u * Mjk * S^v * Mki
// (S = diag(1,1,-1)); all 8 Frobenius errors derived from them.
// ---------------------------------------------------------------------------
__device__ __forceinline__ void compute_errs(
    const float Mij[9], const float Mjk[9], const float Mki[9], float res[8])
{
    float N1[2][9];
#pragma unroll
    for (int p = 0; p < 3; ++p) {
#pragma unroll
        for (int r = 0; r < 3; ++r) {
            float c = Mij[p*3+0] * Mjk[0*3+r] + Mij[p*3+1] * Mjk[1*3+r];
            float d = Mij[p*3+2] * Mjk[2*3+r];
            N1[0][p*3+r] = c + d;
            N1[1][p*3+r] = c - d;
        }
    }
    float err[2][2];
#pragma unroll
    for (int u = 0; u < 2; ++u) {
        float T2p[9], T2m[9];
#pragma unroll
        for (int p = 0; p < 3; ++p) {
#pragma unroll
            for (int s = 0; s < 3; ++s) {
                float c = N1[u][p*3+0] * Mki[0*3+s] + N1[u][p*3+1] * Mki[1*3+s];
                float d = N1[u][p*3+2] * Mki[2*3+s];
                T2p[p*3+s] = c + d;
                T2m[p*3+s] = c - d;
            }
        }
#pragma unroll
        for (int v = 0; v < 2; ++v) {
            const float* T2 = (v == 0) ? T2p : T2m;
            float ss = 0.0f;
#pragma unroll
            for (int e = 0; e < 9; ++e) ss += T2[e] * T2[e];
            float diag = T2[0] + T2[4] + (((u ^ v) & 1) ? -T2[8] : T2[8]);
            float e2 = ss - 2.0f * diag + 3.0f;
            err[u][v] = sqrtf(fmaxf(e2, 0.0f));
        }
    }
#pragma unroll
    for (int m = 0; m < 8; ++m) {
        int a = (m >> 2) & 1, bb = (m >> 1) & 1, c = m & 1;
        res[m] = err[a ^ bb][bb ^ c];
    }
}

// ---------------------------------------------------------------------------
// Cooperative fused kernel.
// Label xcd = blockIdx&7 owns batches 4*xcd..4*xcd+3 and the disjoint R slice
// Rx (2.88 MB fp16, fits per-XCD L2). Correctness never depends on the
// label->hardware-XCD match (slices are disjoint by label); only speed does.
// Phase 1: repack H[b][3i+p][3j+q] -> Rx[(i*N+j)*36 + pq*4 + u]  (fp16)
// Phase 2: gather; unit = (t, uh): 2 batches per thread via dense f16x2 loads.
// ---------------------------------------------------------------------------
__global__ __launch_bounds__(256, 4) void coop_fused_kernel(
    const float* __restrict__ H, const int* __restrict__ trip,
    float* __restrict__ out, _Float16* __restrict__ R)
{
    const int xcd  = blockIdx.x & (NXCD - 1);
    const int rank = blockIdx.x >> 3;           // 0..BPX-1
    const int tid  = threadIdx.x;
    __shared__ _Float16 lds[JR * 36];           // 2880 B

    _Float16* __restrict__ Rx = R + (size_t)xcd * RX_HALFS;

    // ---------------- Phase 1: repack ----------------
    for (int tile = rank; tile < TILES; tile += BPX) {
        int i    = tile / NJT;
        int jt   = tile - i * NJT;
        int col0 = 3 * JR * jt;                 // 120*jt floats, 480B-aligned

        // 360 float4 per tile: (u,p) rows of 30 f4 (120 floats), coalesced
        for (int e = tid; e < 360; e += 256) {
            int u   = e / 90;
            int rem = e - u * 90;
            int p   = rem / 30;
            int c4  = rem - p * 30;
            const float4 v = *reinterpret_cast<const float4*>(
                H + (size_t)(xcd * 4 + u) * (S3 * S3)
                  + (size_t)(3 * i + p) * S3 + col0 + 4 * c4);
            const float vv[4] = {v.x, v.y, v.z, v.w};
#pragma unroll
            for (int x = 0; x < 4; ++x) {
                int c  = 4 * c4 + x;
                int jl = c / 3, q = c - 3 * jl;
                lds[(jl * 9 + p * 3 + q) * 4 + u] = (_Float16)vv[x];
            }
        }
        __syncthreads();

        // 180 x 16B contiguous stores into the Rx slice
        f16x8* dst = reinterpret_cast<f16x8*>(Rx + ((size_t)i * NN + JR * jt) * 36);
        const f16x8* src = reinterpret_cast<const f16x8*>(lds);
        for (int w = tid; w < 180; w += 256)
            dst[w] = src[w];
        __syncthreads();                        // lds reused next tile
    }

    __threadfence();                            // device-scope visibility of Rx
    cooperative_groups::this_grid().sync();

    // ---------------- Phase 2: gather ----------------
    // Units per xcd: 40000 = (t, uh), uh in {0,1} -> batches 4*xcd+2*uh+{0,1}.
    for (int base = 0; base < 2 * TT; base += BPX * 256) {
        int unit = base + rank * 256 + tid;
        if (unit >= 2 * TT) break;
        int t  = unit >> 1;
        int uh = unit & 1;

        int i = trip[3 * t + 0];
        int j = trip[3 * t + 1];
        int k = trip[3 * t + 2];

        // f16x2 at half-index pair*36 + pq*4 + 2*uh  (4B-aligned, dense lines)
        const f16x2* __restrict__ Pij = reinterpret_cast<const f16x2*>(Rx + (size_t)(i * NN + j) * 36 + 2 * uh);
        const f16x2* __restrict__ Pjk = reinterpret_cast<const f16x2*>(Rx + (size_t)(j * NN + k) * 36 + 2 * uh);
        const f16x2* __restrict__ Pki = reinterpret_cast<const f16x2*>(Rx + (size_t)(k * NN + i) * 36 + 2 * uh);

        f16x2 Aij[9], Ajk[9], Aki[9];
#pragma unroll
        for (int pq = 0; pq < 9; ++pq) {
            Aij[pq] = Pij[pq * 2];
            Ajk[pq] = Pjk[pq * 2];
            Aki[pq] = Pki[pq * 2];
        }

#pragma unroll
        for (int uu = 0; uu < 2; ++uu) {        // compile-time after unroll
            float Mij[9], Mjk[9], Mki[9];
#pragma unroll
            for (int pq = 0; pq < 9; ++pq) {
                Mij[pq] = (float)Aij[pq][uu];
                Mjk[pq] = (float)Ajk[pq][uu];
                Mki[pq] = (float)Aki[pq][uu];
            }
            float res[8];
            compute_errs(Mij, Mjk, Mki, res);

            int b = 4 * xcd + 2 * uh + uu;
            f32x4* o4 = reinterpret_cast<f32x4*>(out + ((size_t)b * TT + t) * 8);
            f32x4 lo, hi;
            lo.x = res[0]; lo.y = res[1]; lo.z = res[2]; lo.w = res[3];
            hi.x = res[4]; hi.y = res[5]; hi.z = res[6]; hi.w = res[7];
            __builtin_nontemporal_store(lo, o4);
            __builtin_nontemporal_store(hi, o4 + 1);
        }
    }
}

// ---------------------------------------------------------------------------
// Fallback: R7 fused direct kernel (no workspace / no cooperative needed).
// ---------------------------------------------------------------------------
#define BLKS_PER_B 79
__global__ __launch_bounds__(256) void fused_err_kernel(
    const float* __restrict__ H,
    const int*   __restrict__ trip,
    float*       __restrict__ out)
{
    const int g   = blockIdx.x;
    const int xcd = g & (NXCD - 1);
    const int seq = g >> 3;
    const int bg  = seq / BLKS_PER_B;
    const int b   = bg * NXCD + xcd;
    const int tb  = seq - bg * BLKS_PER_B;
    const int t   = tb * 256 + threadIdx.x;
    if (t >= TT) return;

    const int i = trip[3 * t + 0];
    const int j = trip[3 * t + 1];
    const int k = trip[3 * t + 2];

    const float* __restrict__ Hb = H + (size_t)b * (S3 * S3);

    float Mij[9], Mjk[9], Mki[9];
    const int ri = 3 * i, rj = 3 * j, rk = 3 * k;
#pragma unroll
    for (int p = 0; p < 3; ++p) {
        __builtin_memcpy(&Mij[3*p], Hb + (size_t)(ri + p) * S3 + rj, 12);
        __builtin_memcpy(&Mjk[3*p], Hb + (size_t)(rj + p) * S3 + rk, 12);
        __builtin_memcpy(&Mki[3*p], Hb + (size_t)(rk + p) * S3 + ri, 12);
    }

    float res[8];
    compute_errs(Mij, Mjk, Mki, res);

    f32x4* o4 = reinterpret_cast<f32x4*>(out + ((size_t)b * TT + t) * 8);
    f32x4 lo, hi;
    lo.x = res[0]; lo.y = res[1]; lo.z = res[2]; lo.w = res[3];
    hi.x = res[4]; hi.y = res[5]; hi.z = res[6]; hi.w = res[7];
    __builtin_nontemporal_store(lo, o4);
    __builtin_nontemporal_store(hi, o4 + 1);
}

extern "C" void kernel_launch(void* const* d_in, const int* in_sizes, int n_in,
                              void* d_out, int out_size, void* d_ws, size_t ws_size,
                              hipStream_t stream)
{
    const float* H    = (const float*)d_in[0];
    const int*   trip = (const int*)d_in[1];
    float*       out  = (float*)d_out;

    bool done = false;
    if (ws_size >= R_HALFS * sizeof(_Float16)) {
        _Float16* R = (_Float16*)d_ws;
        void* args[] = {(void*)&H, (void*)&trip, (void*)&out, (void*)&R};
        hipError_t err = hipLaunchCooperativeKernel(
            (const void*)coop_fused_kernel, dim3(COOP_GRID), dim3(256),
            args, 0, stream);
        done = (err == hipSuccess);
    }
    if (!done) {
        const int grid = NXCD * 4 * BLKS_PER_B;   // 2528 blocks
        fused_err_kernel<<<grid, 256, 0, stream>>>(H, trip, out);
    }
}

// Round 9
// 44.941 us; speedup vs baseline: 3.8166x; 3.8166x over previous
//
#include <hip/hip_runtime.h>

// Problem constants (match reference)
#define BQ 32
#define TT 20000
#define NN 200
#define S3 600              // 3*N
#define JT 20               // j's per repack tile (60 floats = 240B runs, 16B-aligned)
#define NTILE (NN / JT)     // 10
#define SLOTS (JT * 9)      // 180
#define RELEMS ((size_t)NN * NN * 9 * BQ)   // 11,520,000 elements; fp16 -> 23.04 MB

typedef float    f32x4 __attribute__((ext_vector_type(4)));
typedef _Float16 f16x8 __attribute__((ext_vector_type(8)));   // 16B
typedef _Float16 f16x4 __attribute__((ext_vector_type(4)));   // 8B
typedef _Float16 f16x2 __attribute__((ext_vector_type(2)));   // 4B

// ---------------------------------------------------------------------------
// Kernel 1: repack H[b][3i+p][3j+q] -> R_f16[((i*N+j)*9 + p*3+q)*32 + b]
// fp32 float4 loads -> fp32 LDS (x33 pad, conflict-free) -> fp16 16B stores.
// (identical to the 32.5us R6 version)
// ---------------------------------------------------------------------------
__global__ __launch_bounds__(256) void repack_kernel(
    const float* __restrict__ H, _Float16* __restrict__ R)
{
    __shared__ float lds[SLOTS * 33];
    const int i   = blockIdx.x / NTILE;
    const int jt  = blockIdx.x % NTILE;
    const int c0  = 3 * JT * jt;        // starting source column (floats)
    const int tid = threadIdx.x;

    const int NE4 = BQ * 3 * 15;        // 1440 float4 per block
    for (int e = tid; e < NE4; e += 256) {
        int b   = e / 45;
        int rem = e - b * 45;
        int p   = rem / 15;
        int c4  = rem - p * 15;
        const float4 v = *reinterpret_cast<const float4*>(
            H + (size_t)b * (S3 * S3) + (size_t)(3 * i + p) * S3 + c0 + 4 * c4);
        const float vv[4] = {v.x, v.y, v.z, v.w};
#pragma unroll
        for (int x = 0; x < 4; ++x) {
            int c  = 4 * c4 + x;
            int jl = c / 3, q = c - 3 * jl;
            lds[(jl * 9 + p * 3 + q) * 33 + b] = vv[x];
        }
    }
    __syncthreads();

    f16x8* dst8 = reinterpret_cast<f16x8*>(R + (size_t)(i * NN + JT * jt) * 9 * BQ);
    const int NW8 = SLOTS * BQ / 8;     // 720
    for (int w = tid; w < NW8; w += 256) {
        int slot = w >> 2;
        int bh   = (w & 3) * 8;
        f16x8 v;
#pragma unroll
        for (int x = 0; x < 8; ++x)
            v[x] = (_Float16)lds[slot * 33 + bh + x];
        dst8[w] = v;
    }
}

// ---------------------------------------------------------------------------
// Shared compute: four distinct products T2[u][v] = Mij * S^u * Mjk * S^v * Mki
// (S = diag(1,1,-1)); all 8 Frobenius errors derived from them.
// ---------------------------------------------------------------------------
__device__ __forceinline__ void compute_errs(
    const float Mij[9], const float Mjk[9], const float Mki[9], float res[8])
{
    float N1[2][9];
#pragma unroll
    for (int p = 0; p < 3; ++p) {
#pragma unroll
        for (int r = 0; r < 3; ++r) {
            float c = Mij[p*3+0] * Mjk[0*3+r] + Mij[p*3+1] * Mjk[1*3+r];
            float d = Mij[p*3+2] * Mjk[2*3+r];
            N1[0][p*3+r] = c + d;
            N1[1][p*3+r] = c - d;
        }
    }
    float err[2][2];
#pragma unroll
    for (int u = 0; u < 2; ++u) {
        float T2p[9], T2m[9];
#pragma unroll
        for (int p = 0; p < 3; ++p) {
#pragma unroll
            for (int s = 0; s < 3; ++s) {
                float c = N1[u][p*3+0] * Mki[0*3+s] + N1[u][p*3+1] * Mki[1*3+s];
                float d = N1[u][p*3+2] * Mki[2*3+s];
                T2p[p*3+s] = c + d;
                T2m[p*3+s] = c - d;
            }
        }
#pragma unroll
        for (int v = 0; v < 2; ++v) {
            const float* T2 = (v == 0) ? T2p : T2m;
            float ss = 0.0f;
#pragma unroll
            for (int e = 0; e < 9; ++e) ss += T2[e] * T2[e];
            float diag = T2[0] + T2[4] + (((u ^ v) & 1) ? -T2[8] : T2[8]);
            float e2 = ss - 2.0f * diag + 3.0f;
            err[u][v] = sqrtf(fmaxf(e2, 0.0f));
        }
    }
#pragma unroll
    for (int m = 0; m < 8; ++m) {
        int a = (m >> 2) & 1, bb = (m >> 1) & 1, c = m & 1;
        res[m] = err[a ^ bb][bb ^ c];
    }
}

// ---------------------------------------------------------------------------
// Kernel 2a (R6's gather): 8 lanes/t, f16x4 loads, 4 batches/thread.
// ---------------------------------------------------------------------------
__global__ __launch_bounds__(256, 2) void gather4_kernel(
    const _Float16* __restrict__ R, const int* __restrict__ trip,
    float* __restrict__ out)
{
    int g  = blockIdx.x * 256 + threadIdx.x;   // 160000 threads exactly
    int bg = g & 7;
    int t  = g >> 3;

    int i = trip[3 * t + 0];
    int j = trip[3 * t + 1];
    int k = trip[3 * t + 2];

    const f16x4* __restrict__ Rij = reinterpret_cast<const f16x4*>(R) + (size_t)(i * NN + j) * 72 + bg;
    const f16x4* __restrict__ Rjk = reinterpret_cast<const f16x4*>(R) + (size_t)(j * NN + k) * 72 + bg;
    const f16x4* __restrict__ Rki = reinterpret_cast<const f16x4*>(R) + (size_t)(k * NN + i) * 72 + bg;

    f16x4 Aij[9], Ajk[9], Aki[9];
#pragma unroll
    for (int pq = 0; pq < 9; ++pq) {
        Aij[pq] = Rij[pq * 8];
        Ajk[pq] = Rjk[pq * 8];
        Aki[pq] = Rki[pq * 8];
    }

#pragma unroll
    for (int u = 0; u < 4; ++u) {
        float Mij[9], Mjk[9], Mki[9];
#pragma unroll
        for (int pq = 0; pq < 9; ++pq) {
            Mij[pq] = (float)Aij[pq][u];
            Mjk[pq] = (float)Ajk[pq][u];
            Mki[pq] = (float)Aki[pq][u];
        }
        float res[8];
        compute_errs(Mij, Mjk, Mki, res);

        int b = 4 * bg + u;
        f32x4* o4 = reinterpret_cast<f32x4*>(out + ((size_t)b * TT + t) * 8);
        f32x4 lo, hi;
        lo.x = res[0]; lo.y = res[1]; lo.z = res[2]; lo.w = res[3];
        hi.x = res[4]; hi.y = res[5]; hi.z = res[6]; hi.w = res[7];
        __builtin_nontemporal_store(lo, o4);
        __builtin_nontemporal_store(hi, o4 + 1);
    }
}

// ---------------------------------------------------------------------------
// Kernel 2b (probe variant): 16 lanes/t, f16x2 loads, 2 batches/thread.
// 320K threads -> ~2x occupancy of gather4; same line traffic.
// Writes the SAME values as gather4 (idempotent re-write; validates itself).
// ---------------------------------------------------------------------------
__global__ __launch_bounds__(256) void gather2_kernel(
    const _Float16* __restrict__ R, const int* __restrict__ trip,
    float* __restrict__ out)
{
    int g  = blockIdx.x * 256 + threadIdx.x;   // 320000 threads exactly
    int bh = g & 15;
    int t  = g >> 4;

    int i = trip[3 * t + 0];
    int j = trip[3 * t + 1];
    int k = trip[3 * t + 2];

    // f16x2 index: pair*144 + pq*16 + bh  (288 halfs per pair = 144 f16x2)
    const f16x2* __restrict__ Rij = reinterpret_cast<const f16x2*>(R) + (size_t)(i * NN + j) * 144 + bh;
    const f16x2* __restrict__ Rjk = reinterpret_cast<const f16x2*>(R) + (size_t)(j * NN + k) * 144 + bh;
    const f16x2* __restrict__ Rki = reinterpret_cast<const f16x2*>(R) + (size_t)(k * NN + i) * 144 + bh;

    f16x2 Aij[9], Ajk[9], Aki[9];
#pragma unroll
    for (int pq = 0; pq < 9; ++pq) {
        Aij[pq] = Rij[pq * 16];
        Ajk[pq] = Rjk[pq * 16];
        Aki[pq] = Rki[pq * 16];
    }

#pragma unroll
    for (int uu = 0; uu < 2; ++uu) {
        float Mij[9], Mjk[9], Mki[9];
#pragma unroll
        for (int pq = 0; pq < 9; ++pq) {
            Mij[pq] = (float)Aij[pq][uu];
            Mjk[pq] = (float)Ajk[pq][uu];
            Mki[pq] = (float)Aki[pq][uu];
        }
        float res[8];
        compute_errs(Mij, Mjk, Mki, res);

        int b = 2 * bh + uu;
        f32x4* o4 = reinterpret_cast<f32x4*>(out + ((size_t)b * TT + t) * 8);
        f32x4 lo, hi;
        lo.x = res[0]; lo.y = res[1]; lo.z = res[2]; lo.w = res[3];
        hi.x = res[4]; hi.y = res[5]; hi.z = res[6]; hi.w = res[7];
        __builtin_nontemporal_store(lo, o4);
        __builtin_nontemporal_store(hi, o4 + 1);
    }
}

// ---------------------------------------------------------------------------
// Fallback (direct kernel) in case ws is too small for R.
// ---------------------------------------------------------------------------
__global__ __launch_bounds__(256) void jcfg_err_direct(
    const float* __restrict__ H,
    const int*   __restrict__ trip,
    float*       __restrict__ out)
{
    int idx = blockIdx.x * blockDim.x + threadIdx.x;
    if (idx >= BQ * TT) return;
    int b = idx / TT;
    int t = idx - b * TT;

    int i = trip[3 * t + 0];
    int j = trip[3 * t + 1];
    int k = trip[3 * t + 2];

    const float* __restrict__ Hb = H + (size_t)b * (S3 * S3);

    float Mij[9], Mjk[9], Mki[9];
    const int ri = 3 * i, rj = 3 * j, rk = 3 * k;
#pragma unroll
    for (int p = 0; p < 3; ++p) {
        __builtin_memcpy(&Mij[3*p], Hb + (size_t)(ri + p) * S3 + rj, 12);
        __builtin_memcpy(&Mjk[3*p], Hb + (size_t)(rj + p) * S3 + rk, 12);
        __builtin_memcpy(&Mki[3*p], Hb + (size_t)(rk + p) * S3 + ri, 12);
    }

    float res[8];
    compute_errs(Mij, Mjk, Mki, res);

    float* o = out + (size_t)idx * 8;
    *reinterpret_cast<float4*>(o)     = make_float4(res[0], res[1], res[2], res[3]);
    *reinterpret_cast<float4*>(o + 4) = make_float4(res[4], res[5], res[6], res[7]);
}

extern "C" void kernel_launch(void* const* d_in, const int* in_sizes, int n_in,
                              void* d_out, int out_size, void* d_ws, size_t ws_size,
                              hipStream_t stream)
{
    const float* H    = (const float*)d_in[0];
    const int*   trip = (const int*)d_in[1];
    float*       out  = (float*)d_out;

    if (ws_size >= RELEMS * sizeof(_Float16)) {
        _Float16* R = (_Float16*)d_ws;
        repack_kernel<<<NN * NTILE, 256, 0, stream>>>(H, R);                // 2000 blocks
        // MEASUREMENT: both gathers write identical full output.
        // dur(this round) - dur(R6) == gather2 duration exactly.
        gather4_kernel<<<(TT * 8)  / 256, 256, 0, stream>>>(R, trip, out);  // 625 blocks
        gather2_kernel<<<(TT * 16) / 256, 256, 0, stream>>>(R, trip, out);  // 1250 blocks
    } else {
        const int total = BQ * TT;
        jcfg_err_direct<<<(total + 255) / 256, 256, 0, stream>>>(H, trip, out);
    }
}